// Round 1
// baseline (243.736 us; speedup 1.0000x reference)
//
#include <hip/hip_runtime.h>

// im2col 3x3 SAME, fp32: x (16,64,128,128) -> out (16,128,128,64,3,3)
// out[b,h,w,c,i,j] = x[b,c,h+i-1,w+j-1] (0 if OOB).
//
// Strategy: write-bound op (604 MB out vs 64 MB in). One block per
// (b, h, 32-wide w tile). Stage x[b, :, h-1:h+2, w0-1:w0+33] (26 KB) in LDS
// with coalesced global reads; do the (w -> c,i,j) transpose as an LDS
// gather; emit fully-coalesced float4 stores.
//
// LDS layout: s[c][rr][cl], cl in [0,34), strides: cl=1, rr=35, c=105.
// s(c,rr,cl) = x[b, c, h-1+rr, w0-1+cl] or 0.
//
// Output per block: 32 pixels x 576 floats = 4608 float4.
// 576 threads: tid -> (pwl = tid/144, r = tid%144). Thread's 4 gather
// offsets off[u] for elements el = 4r+u (c=el/9, ij=el%9) are fixed across
// the 8-pixel-group loop -> zero divisions in the hot loop.

#define NB_H 128
#define NB_W 128
#define NB_C 64
#define WT   32

__global__ __launch_bounds__(576)
void im2col_kernel(const float* __restrict__ x, float* __restrict__ out) {
    __shared__ float s[64 * 105];  // 26880 B

    const int tid = threadIdx.x;
    const int bid = blockIdx.x;
    const int wt = bid & 3;             // W/WT = 4
    const int h  = (bid >> 2) & 127;    // H = 128
    const int b  = bid >> 9;            // 4 * 128 = 512 blocks per batch
    const int w0 = wt * WT;

    // ---- stage input tile: 64 c x 3 rows x 34 cols, coalesced ----
    const float* xb = x + (size_t)b * NB_C * NB_H * NB_W;
    for (int si = tid; si < 64 * 102; si += 576) {
        int c   = si / 102;
        int rem = si - c * 102;
        int rr  = rem / 34;
        int cl  = rem - rr * 34;
        int row = h - 1 + rr;
        int col = w0 - 1 + cl;
        float v = 0.0f;
        if ((unsigned)row < 128u && (unsigned)col < 128u)
            v = xb[(c * 128 + row) * 128 + col];
        s[c * 105 + rr * 35 + cl] = v;
    }

    // ---- per-thread constant gather offsets ----
    const int pwl = tid / 144;      // pixel lane within group of 4
    const int r   = tid - pwl * 144; // float4 slot within pixel [0,144)
    int off[4];
#pragma unroll
    for (int u = 0; u < 4; ++u) {
        int el = r * 4 + u;         // element within 576-float pixel record
        int c  = el / 9;
        int ij = el - c * 9;
        int i  = ij / 3;
        int j  = ij - i * 3;
        off[u] = c * 105 + i * 35 + j;  // + pw gives LDS float index
    }

    __syncthreads();

    // ---- gather from LDS, coalesced float4 stores ----
    float4* outv = (float4*)out;
    const size_t base4 = (((size_t)b * NB_H + h) * NB_W + w0) * 144;
#pragma unroll
    for (int g = 0; g < 8; ++g) {
        int pw = (g << 2) + pwl;    // pixel within tile [0,32)
        float4 v;
        v.x = s[pw + off[0]];
        v.y = s[pw + off[1]];
        v.z = s[pw + off[2]];
        v.w = s[pw + off[3]];
        outv[base4 + (size_t)pw * 144 + r] = v;
    }
}

extern "C" void kernel_launch(void* const* d_in, const int* in_sizes, int n_in,
                              void* d_out, int out_size, void* d_ws, size_t ws_size,
                              hipStream_t stream) {
    const float* x = (const float*)d_in[0];
    float* out = (float*)d_out;
    // blocks = 16 b * 128 h * 4 wtiles = 8192
    im2col_kernel<<<8192, 576, 0, stream>>>(x, out);
}